// Round 20
// baseline (1249.700 us; speedup 1.0000x reference)
//
#include <hip/hip_runtime.h>
#include <hip/hip_bf16.h>
#include <math.h>

// D=6 B=4 N=1024 DIM=768 H=12 DH=64 MLP=3072 ; rows = B*N = 4096
// R20 = R19 + attn split-K 2-way -> 4-way (bf16 partials make the extra partial
// traffic cheap: pO 4-way bf16 = 25.2MB = exactly mbuf). Combine merges 4.
typedef __bf16 bf16;
typedef __bf16 bf16x8 __attribute__((ext_vector_type(8)));
typedef float f32x4 __attribute__((ext_vector_type(4)));

enum { EPI_QKV = 0, EPI_GELU = 1 };

__device__ __forceinline__ void gload16(const void* g, void* s) {
  __builtin_amdgcn_global_load_lds((__attribute__((address_space(1))) void*)g,
                                   (__attribute__((address_space(3))) void*)s, 16, 0, 0);
}

#define MFMA16(a, b, c) __builtin_amdgcn_mfma_f32_16x16x32_bf16((a), (b), (c), 0, 0, 0)

// bijective XCD swizzle (m157/m204): requires nwg % 8 == 0 (all our grids comply)
__device__ __forceinline__ void xcd_swizzle(int& bx, int& by) {
  const int gx = gridDim.x, nwg = gx * gridDim.y;
  int bid = blockIdx.y * gx + blockIdx.x;
  if ((nwg & 7) == 0) bid = (bid & 7) * (nwg >> 3) + (bid >> 3);
  bx = bid % gx;
  by = bid / gx;
}

// ---------------- x fp32 -> float(bf16(x)) -----------------------------------------
__global__ __launch_bounds__(256) void cast_x(const float* __restrict__ x,
                                              float* __restrict__ xq) {
  const int i = (blockIdx.x * 256 + threadIdx.x) * 4;
  float4 v = *(const float4*)(x + i);
  v.x = (float)(bf16)v.x; v.y = (float)(bf16)v.y;
  v.z = (float)(bf16)v.z; v.w = (float)(bf16)v.w;
  *(float4*)(xq + i) = v;
}

// ------ all weights fp32 [K][N] -> bf16 [N][K]; 2 x 64x64 tiles per block ----------
__global__ __launch_bounds__(256) void wconv_all(
    const float* __restrict__ wqkv, const float* __restrict__ wo,
    const float* __restrict__ w1, const float* __restrict__ w2,
    bf16* __restrict__ qkvT, bf16* __restrict__ woT,
    bf16* __restrict__ w1T, bf16* __restrict__ w2T, int lfix) {
  __shared__ float tile[64][65];
  const int t = threadIdx.x;
  const int cx = (t & 15) * 4, ry = t >> 4;

  auto dec = [&](int g, const float*& W, bf16*& Wt, int& K, int& N, int& n0, int& k0) {
    int l, r;
    if (lfix < 0) { l = g / 1728; r = g % 1728; } else { l = lfix; r = g; }
    const int lo = (lfix < 0) ? l : 0;
    int tt;
    if (r < 432)       { W = wqkv + (size_t)l * 768 * 2304; Wt = qkvT + (size_t)lo * 2304 * 768; K = 768;  N = 2304; tt = r; }
    else if (r < 576)  { W = wo   + (size_t)l * 768 * 768;  Wt = woT  + (size_t)lo * 768 * 768;  K = 768;  N = 768;  tt = r - 432; }
    else if (r < 1152) { W = w1   + (size_t)l * 768 * 3072; Wt = w1T  + (size_t)lo * 3072 * 768; K = 768;  N = 3072; tt = r - 576; }
    else               { W = w2   + (size_t)l * 3072 * 768; Wt = w2T  + (size_t)lo * 768 * 3072; K = 3072; N = 768;  tt = r - 1152; }
    const int ntx = N >> 6;
    n0 = (tt % ntx) * 64;
    k0 = (tt / ntx) * 64;
  };

  const int g0 = blockIdx.x * 2;
  const float* W0; bf16* Wt0; int K0, N0, n00, k00;
  const float* W1p; bf16* Wt1; int K1, N1, n01, k01;
  dec(g0, W0, Wt0, K0, N0, n00, k00);
  dec(g0 + 1, W1p, Wt1, K1, N1, n01, k01);

  float4 v0[4], v1[4];
#pragma unroll
  for (int pp = 0; pp < 4; ++pp)
    v0[pp] = *(const float4*)(W0 + (size_t)(k00 + ry + pp * 16) * N0 + n00 + cx);
#pragma unroll
  for (int pp = 0; pp < 4; ++pp)
    v1[pp] = *(const float4*)(W1p + (size_t)(k01 + ry + pp * 16) * N1 + n01 + cx);

  // ---- tile 0 ----
#pragma unroll
  for (int pp = 0; pp < 4; ++pp) {
    const int row = ry + pp * 16;
    tile[row][cx] = v0[pp].x; tile[row][cx + 1] = v0[pp].y;
    tile[row][cx + 2] = v0[pp].z; tile[row][cx + 3] = v0[pp].w;
  }
  __syncthreads();
#pragma unroll
  for (int it = 0; it < 2; ++it) {
    const int c = it * 256 + t;
    const int n = c >> 3, kc = (c & 7) * 8;
    bf16x8 o;
#pragma unroll
    for (int j = 0; j < 8; ++j) o[j] = (bf16)tile[kc + j][n];
    *(bf16x8*)(Wt0 + (size_t)(n00 + n) * K0 + k00 + kc) = o;
  }
  __syncthreads();

  // ---- tile 1 ----
#pragma unroll
  for (int pp = 0; pp < 4; ++pp) {
    const int row = ry + pp * 16;
    tile[row][cx] = v1[pp].x; tile[row][cx + 1] = v1[pp].y;
    tile[row][cx + 2] = v1[pp].z; tile[row][cx + 3] = v1[pp].w;
  }
  __syncthreads();
#pragma unroll
  for (int it = 0; it < 2; ++it) {
    const int c = it * 256 + t;
    const int n = c >> 3, kc = (c & 7) * 8;
    bf16x8 o;
#pragma unroll
    for (int j = 0; j < 8; ++j) o[j] = (bf16)tile[kc + j][n];
    *(bf16x8*)(Wt1 + (size_t)(n01 + n) * K1 + k01 + kc) = o;
  }
}

// ---------------- LayerNorm fp32 -> bf16, one block per row (768) ------------------
__global__ __launch_bounds__(256) void ln_kernel(const float* __restrict__ x,
                                                 const float* __restrict__ g,
                                                 const float* __restrict__ b,
                                                 bf16* __restrict__ out) {
  const int row = blockIdx.x, t = threadIdx.x;
  const float* xr = x + (size_t)row * 768;
  float v0 = xr[t], v1 = xr[t + 256], v2 = xr[t + 512];
  float s = v0 + v1 + v2, sq = v0 * v0 + v1 * v1 + v2 * v2;
#pragma unroll
  for (int m = 32; m; m >>= 1) { s += __shfl_xor(s, m); sq += __shfl_xor(sq, m); }
  __shared__ float rs[4], rq[4];
  const int w = t >> 6;
  if ((t & 63) == 0) { rs[w] = s; rq[w] = sq; }
  __syncthreads();
  s = rs[0] + rs[1] + rs[2] + rs[3];
  sq = rq[0] + rq[1] + rq[2] + rq[3];
  const float mean = s * (1.f / 768.f);
  const float var = sq * (1.f / 768.f) - mean * mean;
  const float rstd = rsqrtf(var + 1e-5f);
  bf16* orow = out + (size_t)row * 768;
  orow[t]       = (bf16)((v0 - mean) * rstd * g[t]       + b[t]);
  orow[t + 256] = (bf16)((v1 - mean) * rstd * g[t + 256] + b[t + 256]);
  orow[t + 512] = (bf16)((v2 - mean) * rstd * g[t + 512] + b[t + 512]);
}

// ---- GEMM 128x128: A[M][K] @ Bt[N][K] -> C, single-A, XCD swizzle -----------------
template <int EPI>
__global__ __launch_bounds__(256) void gemm_s(
    const bf16* __restrict__ A, const bf16* __restrict__ Bt,
    const float* __restrict__ bias, bf16* __restrict__ Cb,
    bf16* __restrict__ qo, bf16* __restrict__ ko_, bf16* __restrict__ vo,
    float* __restrict__ kf, float* __restrict__ vf, int wf,
    int M, int Nc, int K) {
  __shared__ __align__(16) char lds[2][2][8192];  // [buf][A/B][128 rows x 32 k x bf16]
  const int t = threadIdx.x, lane = t & 63, w = t >> 6;
  const int wr = w >> 1, wc = w & 1;
  int bx, by;
  xcd_swizzle(bx, by);
  const size_t m0 = (size_t)by * 128, n0 = (size_t)bx * 128;

  const char* ab[2]; const char* bb[2];
#pragma unroll
  for (int r = 0; r < 2; ++r) {
    int c = r * 256 + t;
    ab[r] = (const char*)(A + (m0 + (c >> 2)) * (size_t)K) + (c & 3) * 16;
    bb[r] = (const char*)(Bt + (n0 + (c >> 2)) * (size_t)K) + (c & 3) * 16;
  }

  f32x4 acc[4][4] = {};

  auto stage = [&](int buf, int tt) {
#pragma unroll
    for (int r = 0; r < 2; ++r) {
      gload16(ab[r] + (size_t)tt * 64, &lds[buf][0][r * 4096 + w * 1024]);
      gload16(bb[r] + (size_t)tt * 64, &lds[buf][1][r * 4096 + w * 1024]);
    }
  };
  auto compute = [&](int buf) {
    const char* As = lds[buf][0];
    const char* Bs = lds[buf][1];
    const int ko = (lane >> 4) * 16;
    bf16x8 af[4], fb[4];
#pragma unroll
    for (int i = 0; i < 4; ++i) {
      af[i] = *(const bf16x8*)(As + (wr * 64 + i * 16 + (lane & 15)) * 64 + ko);
      fb[i] = *(const bf16x8*)(Bs + (wc * 64 + i * 16 + (lane & 15)) * 64 + ko);
    }
#pragma unroll
    for (int mi = 0; mi < 4; ++mi)
#pragma unroll
      for (int ni = 0; ni < 4; ++ni)
        acc[mi][ni] = MFMA16(af[mi], fb[ni], acc[mi][ni]);
  };

  const int NT = K >> 5;
  stage(0, 0);
  __syncthreads();
  int cur = 0;
  for (int tt = 1; tt < NT; ++tt) {
    stage(cur ^ 1, tt);
    compute(cur);
    __syncthreads();
    cur ^= 1;
  }
  compute(cur);

  // epilogue: row = (lane>>4)*4 + i, col = lane&15 within each 16x16 fragment (m89)
#pragma unroll
  for (int mi = 0; mi < 4; ++mi) {
#pragma unroll
    for (int i = 0; i < 4; ++i) {
      size_t row = m0 + wr * 64 + mi * 16 + ((lane >> 4) << 2) + i;
#pragma unroll
      for (int ni = 0; ni < 4; ++ni) {
        size_t col = n0 + wc * 64 + ni * 16 + (lane & 15);
        float v = acc[mi][ni][i];
        if (EPI == EPI_GELU) {
          v += bias[col];
          v = 0.5f * v * (1.f + erff(v * 0.70710678118f));  // exact GELU
          Cb[row * (size_t)Nc + col] = (bf16)v;
        } else {  // EPI_QKV: col in [0,2304) -> (q|k|v, head, d); dst [bh][n][d]
          int b = (int)(row >> 10), n = (int)(row & 1023);
          int which = (int)col >= 1536 ? 2 : ((int)col >= 768 ? 1 : 0);
          int hd = (int)col - which * 768;
          int hh = hd >> 6, d = hd & 63;
          size_t dst = ((size_t)(b * 12 + hh) * 1024 + n) * 64 + d;
          if (which == 0) {
            qo[dst] = (bf16)(v * 0.125f);  // fold DH^-0.5 (pow2: bit-exact)
          } else if (which == 1) {
            ko_[dst] = (bf16)v;
            if (wf) kf[dst] = v;
          } else {
            vo[dst] = (bf16)v;
            if (wf) vf[dst] = v;
          }
        }
      }
    }
  }
}

// ---- GEMM 64x128 tile (N=768 GEMMs: 6x64 = 384 blocks), single-A, bias+res -------
__global__ __launch_bounds__(256) void gemm64_s(
    const bf16* __restrict__ A, const bf16* __restrict__ Bt,
    const float* __restrict__ bias, const float* __restrict__ res,
    float* __restrict__ Cf, int M, int Nc, int K) {
  __shared__ __align__(16) char lds[2][12288];  // [buf][A 4K | B 8K]
  const int t = threadIdx.x, lane = t & 63, w = t >> 6;
  const int wr = w >> 1, wc = w & 1;  // wave = 32 rows x 64 cols
  const int l15 = lane & 15, l4 = lane >> 4;
  int bx, by;
  xcd_swizzle(bx, by);
  const size_t m0 = (size_t)by * 64, n0 = (size_t)bx * 128;

  const char* ab = (const char*)(A + (m0 + (t >> 2)) * (size_t)K) + (t & 3) * 16;
  const char* b0 = (const char*)(Bt + (n0 + (t >> 2)) * (size_t)K) + (t & 3) * 16;
  const char* b1 = (const char*)(Bt + (n0 + 64 + (t >> 2)) * (size_t)K) + (t & 3) * 16;

  f32x4 acc[2][4] = {};

  auto stage = [&](int buf, int tt) {
    gload16(ab + (size_t)tt * 64, &lds[buf][t * 16]);
    gload16(b0 + (size_t)tt * 64, &lds[buf][4096 + t * 16]);
    gload16(b1 + (size_t)tt * 64, &lds[buf][8192 + t * 16]);
  };
  auto compute = [&](int buf) {
    const char* L = lds[buf];
    const int ko = l4 * 16;
    bf16x8 fa[2], fb[4];
#pragma unroll
    for (int mi = 0; mi < 2; ++mi)
      fa[mi] = *(const bf16x8*)(L + (wr * 32 + mi * 16 + l15) * 64 + ko);
#pragma unroll
    for (int ni = 0; ni < 4; ++ni)
      fb[ni] = *(const bf16x8*)(L + 4096 + (wc * 64 + ni * 16 + l15) * 64 + ko);
#pragma unroll
    for (int mi = 0; mi < 2; ++mi)
#pragma unroll
      for (int ni = 0; ni < 4; ++ni)
        acc[mi][ni] = MFMA16(fa[mi], fb[ni], acc[mi][ni]);
  };

  const int NT = K >> 5;
  stage(0, 0);
  __syncthreads();
  int cur = 0;
  for (int tt = 1; tt < NT; ++tt) {
    stage(cur ^ 1, tt);
    compute(cur);
    __syncthreads();
    cur ^= 1;
  }
  compute(cur);

#pragma unroll
  for (int mi = 0; mi < 2; ++mi) {
#pragma unroll
    for (int i = 0; i < 4; ++i) {
      size_t row = m0 + wr * 32 + mi * 16 + l4 * 4 + i;
#pragma unroll
      for (int ni = 0; ni < 4; ++ni) {
        size_t col = n0 + wc * 64 + ni * 16 + l15;
        float v = acc[mi][ni][i] + bias[col] + res[row * (size_t)Nc + col];
        Cf[row * (size_t)Nc + col] = v;
      }
    }
  }
}

// ---------------- v bf16 [bh][n][d] -> vT bf16 [bh][d][n] --------------------------
__global__ __launch_bounds__(256) void vtrans(const bf16* __restrict__ v,
                                              bf16* __restrict__ vT) {
  __shared__ bf16 tile[32][33];
  const int tx = threadIdx.x, ty = threadIdx.y;
  const int bh = blockIdx.x, n0 = blockIdx.y * 32, d0 = blockIdx.z * 32;
  const bf16* vb = v + (size_t)bh * 1024 * 64;
  bf16* vTb = vT + (size_t)bh * 64 * 1024;
#pragma unroll
  for (int r = 0; r < 4; ++r)
    tile[ty + r * 8][tx] = vb[(size_t)(n0 + ty + r * 8) * 64 + d0 + tx];
  __syncthreads();
#pragma unroll
  for (int r = 0; r < 4; ++r)
    vTb[(size_t)(d0 + ty + r * 8) * 1024 + n0 + tx] = tile[tx][ty + r * 8];
}

// ------- flash attention, split-K over grid: block (bh, qb, quarter) ---------------
// quarter z covers kv-blocks 2z..2z+1. Partials: pO bf16 (un-divided), pM/pL fp32.
// 1 wave/block, 32 q-rows; wave-private LDS staging; kv-loop unrolled.
__global__ __launch_bounds__(64) void attn_main(const bf16* __restrict__ q,
                                                const bf16* __restrict__ k,
                                                const bf16* __restrict__ vT,
                                                bf16* __restrict__ pO,
                                                float* __restrict__ pM,
                                                float* __restrict__ pL) {
  __shared__ __align__(16) char Ks[16384];  // [128 keys][64 d] bf16, XOR swz; [0:8K)=P
  __shared__ __align__(16) char Vs[16384];  // [64 d][128 keys] bf16, XOR swz
  char* Ps = Ks;
  const int bh = blockIdx.x, qb = blockIdx.y, sp = blockIdx.z;
  const int lane = threadIdx.x & 63;
  const int l15 = lane & 15, l4 = lane >> 4;

  const char* kp = (const char*)(k + (size_t)bh * 1024 * 64);
  const char* vp = (const char*)(vT + (size_t)bh * 64 * 1024);

  const char* kb0 = kp + (lane >> 3) * 128 + (((lane & 7) ^ ((lane >> 3) & 7)) * 16)
                  + (size_t)sp * 2 * 16384;
  const int vr0 = lane >> 4;
  const char* vb0 = vp + (size_t)vr0 * 2048 + (((lane & 15) ^ vr0) * 16) + sp * 2 * 256;
  const char* vb1 = vp + (size_t)(vr0 + 4) * 2048 + (((lane & 15) ^ (vr0 + 4)) * 16)
                  + sp * 2 * 256;

  bf16x8 aq[2][2];
  {
    const bf16* qbase = q + ((size_t)bh * 1024 + qb * 32) * 64;
#pragma unroll
    for (int mi = 0; mi < 2; ++mi)
#pragma unroll
      for (int ks = 0; ks < 2; ++ks)
        aq[mi][ks] = *(const bf16x8*)(qbase + (mi * 16 + l15) * 64 + ks * 32 + l4 * 8);
  }

  bf16x8 vones;
#pragma unroll
  for (int j = 0; j < 8; ++j) vones[j] = (bf16)1.0f;

  f32x4 oacc[2][4] = {};
  f32x4 lacc[2] = {};
  float mrun[2][4];
#pragma unroll
  for (int mi = 0; mi < 2; ++mi)
#pragma unroll
    for (int i = 0; i < 4; ++i) mrun[mi][i] = -1e30f;

#pragma unroll
  for (int jb = 0; jb < 2; ++jb) {
    // ---- stage K then V (coalesced; wave-private so no barrier) ----
    const char* ksrc = kb0 + (size_t)jb * 16384;
#pragma unroll
    for (int r = 0; r < 16; ++r)
      gload16(ksrc + r * 1024, &Ks[r * 1024]);
    const char* vsrc0 = vb0 + jb * 256;
    const char* vsrc1 = vb1 + jb * 256;
#pragma unroll
    for (int r = 0; r < 8; ++r) {
      gload16(vsrc0 + (size_t)r * 16384, &Vs[r * 2048]);
      gload16(vsrc1 + (size_t)r * 16384, &Vs[r * 2048 + 1024]);
    }
    asm volatile("s_waitcnt vmcnt(16)" ::: "memory");
    __builtin_amdgcn_sched_barrier(0);

    // ---- S = (Q*0.125) K^T ----
    f32x4 sacc[2][8] = {};
#pragma unroll
    for (int ks = 0; ks < 2; ++ks) {
#pragma unroll
      for (int ni = 0; ni < 8; ++ni) {
        const int rr = ni * 16 + l15;
        const bf16x8 bk = *(const bf16x8*)(Ks + rr * 128 + (((ks * 4 + l4) ^ (rr & 7)) * 16));
        sacc[0][ni] = MFMA16(aq[0][ks], bk, sacc[0][ni]);
        sacc[1][ni] = MFMA16(aq[1][ks], bk, sacc[1][ni]);
      }
    }

    // ---- online softmax: max tree + exp (sum via PV ones-column) ----
#pragma unroll
    for (int mi = 0; mi < 2; ++mi) {
#pragma unroll
      for (int i = 0; i < 4; ++i) {
        float mx = sacc[mi][0][i];
#pragma unroll
        for (int ni = 1; ni < 8; ++ni) mx = fmaxf(mx, sacc[mi][ni][i]);
#pragma unroll
        for (int sh = 8; sh; sh >>= 1) mx = fmaxf(mx, __shfl_xor(mx, sh));
        float mnew = fmaxf(mrun[mi][i], mx);
        float alpha = __expf(mrun[mi][i] - mnew);
        mrun[mi][i] = mnew;
#pragma unroll
        for (int ni = 0; ni < 8; ++ni)
          sacc[mi][ni][i] = __expf(sacc[mi][ni][i] - mnew);
#pragma unroll
        for (int ni = 0; ni < 4; ++ni) oacc[mi][ni][i] *= alpha;  // component i (R4 fix)
        lacc[mi][i] *= alpha;
      }
    }

    // ---- P -> LDS (bf16, swizzled; overwrites consumed K rows 0-63) ----
#pragma unroll
    for (int mi = 0; mi < 2; ++mi)
#pragma unroll
      for (int i = 0; i < 4; ++i) {
        int rowl = mi * 16 + l4 * 4 + i;
        char* prp = Ps + rowl * 256;
        int sw = rowl & 7;
#pragma unroll
        for (int ni = 0; ni < 8; ++ni) {
          int col = ni * 16 + l15;
          *(bf16*)(prp + (((col >> 3) ^ sw) * 16) + (col & 7) * 2) = (bf16)sacc[mi][ni][i];
        }
      }

    asm volatile("s_waitcnt vmcnt(0)" ::: "memory");
    __builtin_amdgcn_sched_barrier(0);

    // ---- O += P V ; l += P 1 ----
    const int prow0 = l15, prow1 = 16 + l15;
#pragma unroll
    for (int ks = 0; ks < 4; ++ks) {
      const bf16x8 ap0 = *(const bf16x8*)(Ps + prow0 * 256 + (((ks * 4 + l4) ^ (prow0 & 7)) * 16));
      const bf16x8 ap1 = *(const bf16x8*)(Ps + prow1 * 256 + (((ks * 4 + l4) ^ (prow1 & 7)) * 16));
#pragma unroll
      for (int ni = 0; ni < 4; ++ni) {
        const int vr = ni * 16 + l15;
        const bf16x8 bv = *(const bf16x8*)(Vs + vr * 256 + (((ks * 4 + l4) ^ (vr & 7)) * 16));
        oacc[0][ni] = MFMA16(ap0, bv, oacc[0][ni]);
        oacc[1][ni] = MFMA16(ap1, bv, oacc[1][ni]);
      }
      lacc[0] = MFMA16(ap0, vones, lacc[0]);
      lacc[1] = MFMA16(ap1, vones, lacc[1]);
    }
  }

  // ---- write partials: pO[sp][bh][qb][row][d] bf16 ; pM/pL fp32 per row ----
  const size_t pb = ((size_t)sp * 1536 + bh * 32 + qb) * 32;
#pragma unroll
  for (int mi = 0; mi < 2; ++mi)
#pragma unroll
    for (int i = 0; i < 4; ++i) {
      const int row = mi * 16 + l4 * 4 + i;
      bf16* po = pO + (pb + row) * 64;
#pragma unroll
      for (int ni = 0; ni < 4; ++ni)
        po[ni * 16 + l15] = (bf16)oacc[mi][ni][i];
      if (l15 == 0) {
        pM[pb + row] = mrun[mi][i];
        pL[pb + row] = lacc[mi][i];
      }
    }
}

// ------- combine 4 split-K partials -> bf16 attention output -----------------------
__global__ __launch_bounds__(256) void attn_combine(const bf16* __restrict__ pO,
                                                    const float* __restrict__ pM,
                                                    const float* __restrict__ pL,
                                                    bf16* __restrict__ out) {
  const int blk = blockIdx.x;  // bh*32 + qb
  const int bh = blk >> 5, qb = blk & 31;
  const int t = threadIdx.x;
  const int row = t >> 3, d0 = (t & 7) * 8;
  const size_t base = (size_t)blk * 32 + row;
  float M = pM[base];
#pragma unroll
  for (int p = 1; p < 4; ++p) M = fmaxf(M, pM[(size_t)p * 49152 + base]);
  float L = 0.f;
  float o[8] = {};
#pragma unroll
  for (int p = 0; p < 4; ++p) {
    const float sc = __expf(pM[(size_t)p * 49152 + base] - M);
    L += pL[(size_t)p * 49152 + base] * sc;
    const bf16x8 op = *(const bf16x8*)(pO + ((size_t)p * 49152 + base) * 64 + d0);
#pragma unroll
    for (int j = 0; j < 8; ++j) o[j] += (float)op[j] * sc;
  }
  const float inv = 1.f / L;
  const int b = bh / 12, hh = bh % 12;
  const int n = qb * 32 + row;
  bf16* orow = out + ((size_t)b * 1024 + n) * 768 + hh * 64 + d0;
  bf16x8 ov;
#pragma unroll
  for (int j = 0; j < 8; ++j) ov[j] = (bf16)(o[j] * inv);
  *(bf16x8*)orow = ov;
}

// -----------------------------------------------------------------------------------
extern "C" void kernel_launch(void* const* d_in, const int* in_sizes, int n_in,
                              void* d_out, int out_size, void* d_ws, size_t ws_size,
                              hipStream_t stream) {
  (void)in_sizes; (void)n_in; (void)out_size;
  const float* x_in = (const float*)d_in[0];
  const float* ln1g = (const float*)d_in[1];
  const float* ln1b = (const float*)d_in[2];
  const float* wqkv = (const float*)d_in[3];
  const float* wo   = (const float*)d_in[4];
  const float* bo   = (const float*)d_in[5];
  const float* ln2g = (const float*)d_in[6];
  const float* ln2b = (const float*)d_in[7];
  const float* w1   = (const float*)d_in[8];
  const float* b1   = (const float*)d_in[9];
  const float* w2   = (const float*)d_in[10];
  const float* b2   = (const float*)d_in[11];

  float* outx = (float*)d_out;
  float* outk = outx + (size_t)4096 * 768;
  float* outv = outk + (size_t)4096 * 768;

  char* p = (char*)d_ws;
  auto take = [&](size_t bytes) {
    char* r = p;
    p += (bytes + 255) & ~(size_t)255;
    return r;
  };
  float* xw   = (float*)take((size_t)4096 * 768 * 4);  // fp32 residual (bf16-cast base)
  bf16*  h    = (bf16*)take((size_t)4096 * 768 * 2);
  bf16*  mbuf = (bf16*)take((size_t)4096 * 3072 * 2);  // mlp buf; pO aliases (exact fit)
  bf16*  qbuf = (bf16*)take((size_t)4096 * 768 * 2);
  bf16*  kbuf = (bf16*)take((size_t)4096 * 768 * 2);
  bf16*  vbuf = (bf16*)take((size_t)4096 * 768 * 2);
  bf16*  vTb  = (bf16*)take((size_t)4096 * 768 * 2);
  bf16*  abuf = (bf16*)take((size_t)4096 * 768 * 2);
  float* pM   = (float*)take((size_t)4 * 49152 * 4);
  float* pL   = (float*)take((size_t)4 * 49152 * 4);
  bf16*  pO   = mbuf;  // 4 x 49152 x 64 x 2B = 25.17MB = mbuf size (dead during attn)

  const size_t wq1 = (size_t)2304 * 768, wo1 = (size_t)768 * 768,
               w11 = (size_t)3072 * 768, w21 = (size_t)768 * 3072;
  const size_t used = (size_t)(p - (char*)d_ws);
  const size_t wbytes = (wq1 + wo1 + w11 + w21) * 2;
  const bool hoist = ws_size >= used + 6 * wbytes + 8192;
  const int nl = hoist ? 6 : 1;
  bf16* qkvT = (bf16*)take(wq1 * 2 * nl);
  bf16* woT  = (bf16*)take(wo1 * 2 * nl);
  bf16* w1T  = (bf16*)take(w11 * 2 * nl);
  bf16* w2T  = (bf16*)take(w21 * 2 * nl);

  cast_x<<<3072, 256, 0, stream>>>(x_in, xw);
  if (hoist)
    wconv_all<<<5184, 256, 0, stream>>>(wqkv, wo, w1, w2, qkvT, woT, w1T, w2T, -1);

  for (int l = 0; l < 6; ++l) {
    if (!hoist)
      wconv_all<<<864, 256, 0, stream>>>(wqkv, wo, w1, w2, qkvT, woT, w1T, w2T, l);
    bf16* qkL = qkvT + (hoist ? (size_t)l * wq1 : 0);
    bf16* woL = woT  + (hoist ? (size_t)l * wo1 : 0);
    bf16* w1L = w1T  + (hoist ? (size_t)l * w11 : 0);
    bf16* w2L = w2T  + (hoist ? (size_t)l * w21 : 0);

    ln_kernel<<<4096, 256, 0, stream>>>(xw, ln1g + l * 768, ln1b + l * 768, h);
    gemm_s<EPI_QKV><<<dim3(18, 32), 256, 0, stream>>>(
        h, qkL, nullptr, nullptr, qbuf, kbuf, vbuf, outk, outv, l == 5 ? 1 : 0,
        4096, 2304, 768);
    vtrans<<<dim3(48, 32, 2), dim3(32, 8), 0, stream>>>(vbuf, vTb);
    attn_main<<<dim3(48, 32, 4), 64, 0, stream>>>(qbuf, kbuf, vTb, pO, pM, pL);
    attn_combine<<<1536, 256, 0, stream>>>(pO, pM, pL, abuf);
    gemm64_s<<<dim3(6, 64), 256, 0, stream>>>(
        abuf, woL, bo + l * 768, xw, xw, 4096, 768, 768);
    ln_kernel<<<4096, 256, 0, stream>>>(xw, ln2g + l * 768, ln2b + l * 768, h);
    gemm_s<EPI_GELU><<<dim3(24, 32), 256, 0, stream>>>(
        h, w1L, b1 + l * 3072, mbuf, nullptr, nullptr, nullptr, nullptr, nullptr, 0,
        4096, 3072, 768);
    // last layer writes the final residual directly to d_out (drops the memcpy)
    gemm64_s<<<dim3(6, 64), 256, 0, stream>>>(
        mbuf, w2L, b2 + l * 768, xw, (l == 5) ? outx : xw, 4096, 768, 3072);
  }
}

// Round 21
// 1215.245 us; speedup vs baseline: 1.0284x; 1.0284x over previous
//
#include <hip/hip_runtime.h>
#include <hip/hip_bf16.h>
#include <math.h>

// D=6 B=4 N=1024 DIM=768 H=12 DH=64 MLP=3072 ; rows = B*N = 4096
// R21 = R19 exact (measured best: 1216.4us). 2-way split-K attention with bf16
// partials (pO aliases dead mlp buffer), sum-via-MFMA, wave-private LDS staging;
// single-bf16 activations; exact-bf16 weights; fp32 residual; wconv 2 tiles/block.
typedef __bf16 bf16;
typedef __bf16 bf16x8 __attribute__((ext_vector_type(8)));
typedef float f32x4 __attribute__((ext_vector_type(4)));

enum { EPI_QKV = 0, EPI_GELU = 1 };

__device__ __forceinline__ void gload16(const void* g, void* s) {
  __builtin_amdgcn_global_load_lds((__attribute__((address_space(1))) void*)g,
                                   (__attribute__((address_space(3))) void*)s, 16, 0, 0);
}

#define MFMA16(a, b, c) __builtin_amdgcn_mfma_f32_16x16x32_bf16((a), (b), (c), 0, 0, 0)

// bijective XCD swizzle (m157/m204): requires nwg % 8 == 0 (all our grids comply)
__device__ __forceinline__ void xcd_swizzle(int& bx, int& by) {
  const int gx = gridDim.x, nwg = gx * gridDim.y;
  int bid = blockIdx.y * gx + blockIdx.x;
  if ((nwg & 7) == 0) bid = (bid & 7) * (nwg >> 3) + (bid >> 3);
  bx = bid % gx;
  by = bid / gx;
}

// ---------------- x fp32 -> float(bf16(x)) -----------------------------------------
__global__ __launch_bounds__(256) void cast_x(const float* __restrict__ x,
                                              float* __restrict__ xq) {
  const int i = (blockIdx.x * 256 + threadIdx.x) * 4;
  float4 v = *(const float4*)(x + i);
  v.x = (float)(bf16)v.x; v.y = (float)(bf16)v.y;
  v.z = (float)(bf16)v.z; v.w = (float)(bf16)v.w;
  *(float4*)(xq + i) = v;
}

// ------ all weights fp32 [K][N] -> bf16 [N][K]; 2 x 64x64 tiles per block ----------
__global__ __launch_bounds__(256) void wconv_all(
    const float* __restrict__ wqkv, const float* __restrict__ wo,
    const float* __restrict__ w1, const float* __restrict__ w2,
    bf16* __restrict__ qkvT, bf16* __restrict__ woT,
    bf16* __restrict__ w1T, bf16* __restrict__ w2T, int lfix) {
  __shared__ float tile[64][65];
  const int t = threadIdx.x;
  const int cx = (t & 15) * 4, ry = t >> 4;

  auto dec = [&](int g, const float*& W, bf16*& Wt, int& K, int& N, int& n0, int& k0) {
    int l, r;
    if (lfix < 0) { l = g / 1728; r = g % 1728; } else { l = lfix; r = g; }
    const int lo = (lfix < 0) ? l : 0;
    int tt;
    if (r < 432)       { W = wqkv + (size_t)l * 768 * 2304; Wt = qkvT + (size_t)lo * 2304 * 768; K = 768;  N = 2304; tt = r; }
    else if (r < 576)  { W = wo   + (size_t)l * 768 * 768;  Wt = woT  + (size_t)lo * 768 * 768;  K = 768;  N = 768;  tt = r - 432; }
    else if (r < 1152) { W = w1   + (size_t)l * 768 * 3072; Wt = w1T  + (size_t)lo * 3072 * 768; K = 768;  N = 3072; tt = r - 576; }
    else               { W = w2   + (size_t)l * 3072 * 768; Wt = w2T  + (size_t)lo * 768 * 3072; K = 3072; N = 768;  tt = r - 1152; }
    const int ntx = N >> 6;
    n0 = (tt % ntx) * 64;
    k0 = (tt / ntx) * 64;
  };

  const int g0 = blockIdx.x * 2;
  const float* W0; bf16* Wt0; int K0, N0, n00, k00;
  const float* W1p; bf16* Wt1; int K1, N1, n01, k01;
  dec(g0, W0, Wt0, K0, N0, n00, k00);
  dec(g0 + 1, W1p, Wt1, K1, N1, n01, k01);

  float4 v0[4], v1[4];
#pragma unroll
  for (int pp = 0; pp < 4; ++pp)
    v0[pp] = *(const float4*)(W0 + (size_t)(k00 + ry + pp * 16) * N0 + n00 + cx);
#pragma unroll
  for (int pp = 0; pp < 4; ++pp)
    v1[pp] = *(const float4*)(W1p + (size_t)(k01 + ry + pp * 16) * N1 + n01 + cx);

  // ---- tile 0 ----
#pragma unroll
  for (int pp = 0; pp < 4; ++pp) {
    const int row = ry + pp * 16;
    tile[row][cx] = v0[pp].x; tile[row][cx + 1] = v0[pp].y;
    tile[row][cx + 2] = v0[pp].z; tile[row][cx + 3] = v0[pp].w;
  }
  __syncthreads();
#pragma unroll
  for (int it = 0; it < 2; ++it) {
    const int c = it * 256 + t;
    const int n = c >> 3, kc = (c & 7) * 8;
    bf16x8 o;
#pragma unroll
    for (int j = 0; j < 8; ++j) o[j] = (bf16)tile[kc + j][n];
    *(bf16x8*)(Wt0 + (size_t)(n00 + n) * K0 + k00 + kc) = o;
  }
  __syncthreads();

  // ---- tile 1 ----
#pragma unroll
  for (int pp = 0; pp < 4; ++pp) {
    const int row = ry + pp * 16;
    tile[row][cx] = v1[pp].x; tile[row][cx + 1] = v1[pp].y;
    tile[row][cx + 2] = v1[pp].z; tile[row][cx + 3] = v1[pp].w;
  }
  __syncthreads();
#pragma unroll
  for (int it = 0; it < 2; ++it) {
    const int c = it * 256 + t;
    const int n = c >> 3, kc = (c & 7) * 8;
    bf16x8 o;
#pragma unroll
    for (int j = 0; j < 8; ++j) o[j] = (bf16)tile[kc + j][n];
    *(bf16x8*)(Wt1 + (size_t)(n01 + n) * K1 + k01 + kc) = o;
  }
}

// ---------------- LayerNorm fp32 -> bf16, one block per row (768) ------------------
__global__ __launch_bounds__(256) void ln_kernel(const float* __restrict__ x,
                                                 const float* __restrict__ g,
                                                 const float* __restrict__ b,
                                                 bf16* __restrict__ out) {
  const int row = blockIdx.x, t = threadIdx.x;
  const float* xr = x + (size_t)row * 768;
  float v0 = xr[t], v1 = xr[t + 256], v2 = xr[t + 512];
  float s = v0 + v1 + v2, sq = v0 * v0 + v1 * v1 + v2 * v2;
#pragma unroll
  for (int m = 32; m; m >>= 1) { s += __shfl_xor(s, m); sq += __shfl_xor(sq, m); }
  __shared__ float rs[4], rq[4];
  const int w = t >> 6;
  if ((t & 63) == 0) { rs[w] = s; rq[w] = sq; }
  __syncthreads();
  s = rs[0] + rs[1] + rs[2] + rs[3];
  sq = rq[0] + rq[1] + rq[2] + rq[3];
  const float mean = s * (1.f / 768.f);
  const float var = sq * (1.f / 768.f) - mean * mean;
  const float rstd = rsqrtf(var + 1e-5f);
  bf16* orow = out + (size_t)row * 768;
  orow[t]       = (bf16)((v0 - mean) * rstd * g[t]       + b[t]);
  orow[t + 256] = (bf16)((v1 - mean) * rstd * g[t + 256] + b[t + 256]);
  orow[t + 512] = (bf16)((v2 - mean) * rstd * g[t + 512] + b[t + 512]);
}

// ---- GEMM 128x128: A[M][K] @ Bt[N][K] -> C, single-A, XCD swizzle -----------------
template <int EPI>
__global__ __launch_bounds__(256) void gemm_s(
    const bf16* __restrict__ A, const bf16* __restrict__ Bt,
    const float* __restrict__ bias, bf16* __restrict__ Cb,
    bf16* __restrict__ qo, bf16* __restrict__ ko_, bf16* __restrict__ vo,
    float* __restrict__ kf, float* __restrict__ vf, int wf,
    int M, int Nc, int K) {
  __shared__ __align__(16) char lds[2][2][8192];  // [buf][A/B][128 rows x 32 k x bf16]
  const int t = threadIdx.x, lane = t & 63, w = t >> 6;
  const int wr = w >> 1, wc = w & 1;
  int bx, by;
  xcd_swizzle(bx, by);
  const size_t m0 = (size_t)by * 128, n0 = (size_t)bx * 128;

  const char* ab[2]; const char* bb[2];
#pragma unroll
  for (int r = 0; r < 2; ++r) {
    int c = r * 256 + t;
    ab[r] = (const char*)(A + (m0 + (c >> 2)) * (size_t)K) + (c & 3) * 16;
    bb[r] = (const char*)(Bt + (n0 + (c >> 2)) * (size_t)K) + (c & 3) * 16;
  }

  f32x4 acc[4][4] = {};

  auto stage = [&](int buf, int tt) {
#pragma unroll
    for (int r = 0; r < 2; ++r) {
      gload16(ab[r] + (size_t)tt * 64, &lds[buf][0][r * 4096 + w * 1024]);
      gload16(bb[r] + (size_t)tt * 64, &lds[buf][1][r * 4096 + w * 1024]);
    }
  };
  auto compute = [&](int buf) {
    const char* As = lds[buf][0];
    const char* Bs = lds[buf][1];
    const int ko = (lane >> 4) * 16;
    bf16x8 af[4], fb[4];
#pragma unroll
    for (int i = 0; i < 4; ++i) {
      af[i] = *(const bf16x8*)(As + (wr * 64 + i * 16 + (lane & 15)) * 64 + ko);
      fb[i] = *(const bf16x8*)(Bs + (wc * 64 + i * 16 + (lane & 15)) * 64 + ko);
    }
#pragma unroll
    for (int mi = 0; mi < 4; ++mi)
#pragma unroll
      for (int ni = 0; ni < 4; ++ni)
        acc[mi][ni] = MFMA16(af[mi], fb[ni], acc[mi][ni]);
  };

  const int NT = K >> 5;
  stage(0, 0);
  __syncthreads();
  int cur = 0;
  for (int tt = 1; tt < NT; ++tt) {
    stage(cur ^ 1, tt);
    compute(cur);
    __syncthreads();
    cur ^= 1;
  }
  compute(cur);

  // epilogue: row = (lane>>4)*4 + i, col = lane&15 within each 16x16 fragment (m89)
#pragma unroll
  for (int mi = 0; mi < 4; ++mi) {
#pragma unroll
    for (int i = 0; i < 4; ++i) {
      size_t row = m0 + wr * 64 + mi * 16 + ((lane >> 4) << 2) + i;
#pragma unroll
      for (int ni = 0; ni < 4; ++ni) {
        size_t col = n0 + wc * 64 + ni * 16 + (lane & 15);
        float v = acc[mi][ni][i];
        if (EPI == EPI_GELU) {
          v += bias[col];
          v = 0.5f * v * (1.f + erff(v * 0.70710678118f));  // exact GELU
          Cb[row * (size_t)Nc + col] = (bf16)v;
        } else {  // EPI_QKV: col in [0,2304) -> (q|k|v, head, d); dst [bh][n][d]
          int b = (int)(row >> 10), n = (int)(row & 1023);
          int which = (int)col >= 1536 ? 2 : ((int)col >= 768 ? 1 : 0);
          int hd = (int)col - which * 768;
          int hh = hd >> 6, d = hd & 63;
          size_t dst = ((size_t)(b * 12 + hh) * 1024 + n) * 64 + d;
          if (which == 0) {
            qo[dst] = (bf16)(v * 0.125f);  // fold DH^-0.5 (pow2: bit-exact)
          } else if (which == 1) {
            ko_[dst] = (bf16)v;
            if (wf) kf[dst] = v;
          } else {
            vo[dst] = (bf16)v;
            if (wf) vf[dst] = v;
          }
        }
      }
    }
  }
}

// ---- GEMM 64x128 tile (N=768 GEMMs: 6x64 = 384 blocks), single-A, bias+res -------
__global__ __launch_bounds__(256) void gemm64_s(
    const bf16* __restrict__ A, const bf16* __restrict__ Bt,
    const float* __restrict__ bias, const float* __restrict__ res,
    float* __restrict__ Cf, int M, int Nc, int K) {
  __shared__ __align__(16) char lds[2][12288];  // [buf][A 4K | B 8K]
  const int t = threadIdx.x, lane = t & 63, w = t >> 6;
  const int wr = w >> 1, wc = w & 1;  // wave = 32 rows x 64 cols
  const int l15 = lane & 15, l4 = lane >> 4;
  int bx, by;
  xcd_swizzle(bx, by);
  const size_t m0 = (size_t)by * 64, n0 = (size_t)bx * 128;

  const char* ab = (const char*)(A + (m0 + (t >> 2)) * (size_t)K) + (t & 3) * 16;
  const char* b0 = (const char*)(Bt + (n0 + (t >> 2)) * (size_t)K) + (t & 3) * 16;
  const char* b1 = (const char*)(Bt + (n0 + 64 + (t >> 2)) * (size_t)K) + (t & 3) * 16;

  f32x4 acc[2][4] = {};

  auto stage = [&](int buf, int tt) {
    gload16(ab + (size_t)tt * 64, &lds[buf][t * 16]);
    gload16(b0 + (size_t)tt * 64, &lds[buf][4096 + t * 16]);
    gload16(b1 + (size_t)tt * 64, &lds[buf][8192 + t * 16]);
  };
  auto compute = [&](int buf) {
    const char* L = lds[buf];
    const int ko = l4 * 16;
    bf16x8 fa[2], fb[4];
#pragma unroll
    for (int mi = 0; mi < 2; ++mi)
      fa[mi] = *(const bf16x8*)(L + (wr * 32 + mi * 16 + l15) * 64 + ko);
#pragma unroll
    for (int ni = 0; ni < 4; ++ni)
      fb[ni] = *(const bf16x8*)(L + 4096 + (wc * 64 + ni * 16 + l15) * 64 + ko);
#pragma unroll
    for (int mi = 0; mi < 2; ++mi)
#pragma unroll
      for (int ni = 0; ni < 4; ++ni)
        acc[mi][ni] = MFMA16(fa[mi], fb[ni], acc[mi][ni]);
  };

  const int NT = K >> 5;
  stage(0, 0);
  __syncthreads();
  int cur = 0;
  for (int tt = 1; tt < NT; ++tt) {
    stage(cur ^ 1, tt);
    compute(cur);
    __syncthreads();
    cur ^= 1;
  }
  compute(cur);

#pragma unroll
  for (int mi = 0; mi < 2; ++mi) {
#pragma unroll
    for (int i = 0; i < 4; ++i) {
      size_t row = m0 + wr * 32 + mi * 16 + l4 * 4 + i;
#pragma unroll
      for (int ni = 0; ni < 4; ++ni) {
        size_t col = n0 + wc * 64 + ni * 16 + l15;
        float v = acc[mi][ni][i] + bias[col] + res[row * (size_t)Nc + col];
        Cf[row * (size_t)Nc + col] = v;
      }
    }
  }
}

// ---------------- v bf16 [bh][n][d] -> vT bf16 [bh][d][n] --------------------------
__global__ __launch_bounds__(256) void vtrans(const bf16* __restrict__ v,
                                              bf16* __restrict__ vT) {
  __shared__ bf16 tile[32][33];
  const int tx = threadIdx.x, ty = threadIdx.y;
  const int bh = blockIdx.x, n0 = blockIdx.y * 32, d0 = blockIdx.z * 32;
  const bf16* vb = v + (size_t)bh * 1024 * 64;
  bf16* vTb = vT + (size_t)bh * 64 * 1024;
#pragma unroll
  for (int r = 0; r < 4; ++r)
    tile[ty + r * 8][tx] = vb[(size_t)(n0 + ty + r * 8) * 64 + d0 + tx];
  __syncthreads();
#pragma unroll
  for (int r = 0; r < 4; ++r)
    vTb[(size_t)(d0 + ty + r * 8) * 1024 + n0 + tx] = tile[tx][ty + r * 8];
}

// ------- flash attention, split-K over grid: block (bh, qb, half) ------------------
// half z covers kv-blocks 4z..4z+3. Partials: pO bf16 (un-divided), pM, pL fp32.
// 1 wave/block, 32 q-rows; wave-private LDS staging; kv-loop unrolled.
__global__ __launch_bounds__(64) void attn_main(const bf16* __restrict__ q,
                                                const bf16* __restrict__ k,
                                                const bf16* __restrict__ vT,
                                                bf16* __restrict__ pO,
                                                float* __restrict__ pM,
                                                float* __restrict__ pL) {
  __shared__ __align__(16) char Ks[16384];  // [128 keys][64 d] bf16, XOR swz; [0:8K)=P
  __shared__ __align__(16) char Vs[16384];  // [64 d][128 keys] bf16, XOR swz
  char* Ps = Ks;
  const int bh = blockIdx.x, qb = blockIdx.y, half = blockIdx.z;
  const int lane = threadIdx.x & 63;
  const int l15 = lane & 15, l4 = lane >> 4;

  const char* kp = (const char*)(k + (size_t)bh * 1024 * 64);
  const char* vp = (const char*)(vT + (size_t)bh * 64 * 1024);

  const char* kb0 = kp + (lane >> 3) * 128 + (((lane & 7) ^ ((lane >> 3) & 7)) * 16)
                  + (size_t)half * 4 * 16384;
  const int vr0 = lane >> 4;
  const char* vb0 = vp + (size_t)vr0 * 2048 + (((lane & 15) ^ vr0) * 16) + half * 4 * 256;
  const char* vb1 = vp + (size_t)(vr0 + 4) * 2048 + (((lane & 15) ^ (vr0 + 4)) * 16)
                  + half * 4 * 256;

  bf16x8 aq[2][2];
  {
    const bf16* qbase = q + ((size_t)bh * 1024 + qb * 32) * 64;
#pragma unroll
    for (int mi = 0; mi < 2; ++mi)
#pragma unroll
      for (int ks = 0; ks < 2; ++ks)
        aq[mi][ks] = *(const bf16x8*)(qbase + (mi * 16 + l15) * 64 + ks * 32 + l4 * 8);
  }

  bf16x8 vones;
#pragma unroll
  for (int j = 0; j < 8; ++j) vones[j] = (bf16)1.0f;

  f32x4 oacc[2][4] = {};
  f32x4 lacc[2] = {};
  float mrun[2][4];
#pragma unroll
  for (int mi = 0; mi < 2; ++mi)
#pragma unroll
    for (int i = 0; i < 4; ++i) mrun[mi][i] = -1e30f;

#pragma unroll
  for (int jb = 0; jb < 4; ++jb) {
    // ---- stage K then V (coalesced; wave-private so no barrier) ----
    const char* ksrc = kb0 + (size_t)jb * 16384;
#pragma unroll
    for (int r = 0; r < 16; ++r)
      gload16(ksrc + r * 1024, &Ks[r * 1024]);
    const char* vsrc0 = vb0 + jb * 256;
    const char* vsrc1 = vb1 + jb * 256;
#pragma unroll
    for (int r = 0; r < 8; ++r) {
      gload16(vsrc0 + (size_t)r * 16384, &Vs[r * 2048]);
      gload16(vsrc1 + (size_t)r * 16384, &Vs[r * 2048 + 1024]);
    }
    asm volatile("s_waitcnt vmcnt(16)" ::: "memory");
    __builtin_amdgcn_sched_barrier(0);

    // ---- S = (Q*0.125) K^T ----
    f32x4 sacc[2][8] = {};
#pragma unroll
    for (int ks = 0; ks < 2; ++ks) {
#pragma unroll
      for (int ni = 0; ni < 8; ++ni) {
        const int rr = ni * 16 + l15;
        const bf16x8 bk = *(const bf16x8*)(Ks + rr * 128 + (((ks * 4 + l4) ^ (rr & 7)) * 16));
        sacc[0][ni] = MFMA16(aq[0][ks], bk, sacc[0][ni]);
        sacc[1][ni] = MFMA16(aq[1][ks], bk, sacc[1][ni]);
      }
    }

    // ---- online softmax: max tree + exp (sum via PV ones-column) ----
#pragma unroll
    for (int mi = 0; mi < 2; ++mi) {
#pragma unroll
      for (int i = 0; i < 4; ++i) {
        float mx = sacc[mi][0][i];
#pragma unroll
        for (int ni = 1; ni < 8; ++ni) mx = fmaxf(mx, sacc[mi][ni][i]);
#pragma unroll
        for (int sh = 8; sh; sh >>= 1) mx = fmaxf(mx, __shfl_xor(mx, sh));
        float mnew = fmaxf(mrun[mi][i], mx);
        float alpha = __expf(mrun[mi][i] - mnew);
        mrun[mi][i] = mnew;
#pragma unroll
        for (int ni = 0; ni < 8; ++ni)
          sacc[mi][ni][i] = __expf(sacc[mi][ni][i] - mnew);
#pragma unroll
        for (int ni = 0; ni < 4; ++ni) oacc[mi][ni][i] *= alpha;  // component i (R4 fix)
        lacc[mi][i] *= alpha;
      }
    }

    // ---- P -> LDS (bf16, swizzled; overwrites consumed K rows 0-63) ----
#pragma unroll
    for (int mi = 0; mi < 2; ++mi)
#pragma unroll
      for (int i = 0; i < 4; ++i) {
        int rowl = mi * 16 + l4 * 4 + i;
        char* prp = Ps + rowl * 256;
        int sw = rowl & 7;
#pragma unroll
        for (int ni = 0; ni < 8; ++ni) {
          int col = ni * 16 + l15;
          *(bf16*)(prp + (((col >> 3) ^ sw) * 16) + (col & 7) * 2) = (bf16)sacc[mi][ni][i];
        }
      }

    asm volatile("s_waitcnt vmcnt(0)" ::: "memory");
    __builtin_amdgcn_sched_barrier(0);

    // ---- O += P V ; l += P 1 ----
    const int prow0 = l15, prow1 = 16 + l15;
#pragma unroll
    for (int ks = 0; ks < 4; ++ks) {
      const bf16x8 ap0 = *(const bf16x8*)(Ps + prow0 * 256 + (((ks * 4 + l4) ^ (prow0 & 7)) * 16));
      const bf16x8 ap1 = *(const bf16x8*)(Ps + prow1 * 256 + (((ks * 4 + l4) ^ (prow1 & 7)) * 16));
#pragma unroll
      for (int ni = 0; ni < 4; ++ni) {
        const int vr = ni * 16 + l15;
        const bf16x8 bv = *(const bf16x8*)(Vs + vr * 256 + (((ks * 4 + l4) ^ (vr & 7)) * 16));
        oacc[0][ni] = MFMA16(ap0, bv, oacc[0][ni]);
        oacc[1][ni] = MFMA16(ap1, bv, oacc[1][ni]);
      }
      lacc[0] = MFMA16(ap0, vones, lacc[0]);
      lacc[1] = MFMA16(ap1, vones, lacc[1]);
    }
  }

  // ---- write partials: pO[half][bh][qb][row][d] bf16 ; pM/pL fp32 per row ----
  const size_t pb = ((size_t)half * 1536 + bh * 32 + qb) * 32;
#pragma unroll
  for (int mi = 0; mi < 2; ++mi)
#pragma unroll
    for (int i = 0; i < 4; ++i) {
      const int row = mi * 16 + l4 * 4 + i;
      bf16* po = pO + (pb + row) * 64;
#pragma unroll
      for (int ni = 0; ni < 4; ++ni)
        po[ni * 16 + l15] = (bf16)oacc[mi][ni][i];
      if (l15 == 0) {
        pM[pb + row] = mrun[mi][i];
        pL[pb + row] = lacc[mi][i];
      }
    }
}

// ------- combine the two split-K halves -> bf16 attention output -------------------
__global__ __launch_bounds__(256) void attn_combine(const bf16* __restrict__ pO,
                                                    const float* __restrict__ pM,
                                                    const float* __restrict__ pL,
                                                    bf16* __restrict__ out) {
  const int blk = blockIdx.x;  // bh*32 + qb
  const int bh = blk >> 5, qb = blk & 31;
  const int t = threadIdx.x;
  const int row = t >> 3, d0 = (t & 7) * 8;
  const size_t base = (size_t)blk * 32 + row;
  const float m0 = pM[base], m1 = pM[49152 + base];
  const float M = fmaxf(m0, m1);
  const float s0 = __expf(m0 - M), s1 = __expf(m1 - M);
  const float L = pL[base] * s0 + pL[49152 + base] * s1;
  const float inv = 1.f / L;
  const bf16x8 p0 = *(const bf16x8*)(pO + base * 64 + d0);
  const bf16x8 p1 = *(const bf16x8*)(pO + (size_t)49152 * 64 + base * 64 + d0);
  const int b = bh / 12, hh = bh % 12;
  const int n = qb * 32 + row;
  bf16* orow = out + ((size_t)b * 1024 + n) * 768 + hh * 64 + d0;
  bf16x8 ov;
#pragma unroll
  for (int j = 0; j < 8; ++j)
    ov[j] = (bf16)(((float)p0[j] * s0 + (float)p1[j] * s1) * inv);
  *(bf16x8*)orow = ov;
}

// -----------------------------------------------------------------------------------
extern "C" void kernel_launch(void* const* d_in, const int* in_sizes, int n_in,
                              void* d_out, int out_size, void* d_ws, size_t ws_size,
                              hipStream_t stream) {
  (void)in_sizes; (void)n_in; (void)out_size;
  const float* x_in = (const float*)d_in[0];
  const float* ln1g = (const float*)d_in[1];
  const float* ln1b = (const float*)d_in[2];
  const float* wqkv = (const float*)d_in[3];
  const float* wo   = (const float*)d_in[4];
  const float* bo   = (const float*)d_in[5];
  const float* ln2g = (const float*)d_in[6];
  const float* ln2b = (const float*)d_in[7];
  const float* w1   = (const float*)d_in[8];
  const float* b1   = (const float*)d_in[9];
  const float* w2   = (const float*)d_in[10];
  const float* b2   = (const float*)d_in[11];

  float* outx = (float*)d_out;
  float* outk = outx + (size_t)4096 * 768;
  float* outv = outk + (size_t)4096 * 768;

  char* p = (char*)d_ws;
  auto take = [&](size_t bytes) {
    char* r = p;
    p += (bytes + 255) & ~(size_t)255;
    return r;
  };
  float* xw   = (float*)take((size_t)4096 * 768 * 4);  // fp32 residual (bf16-cast base)
  bf16*  h    = (bf16*)take((size_t)4096 * 768 * 2);
  bf16*  mbuf = (bf16*)take((size_t)4096 * 3072 * 2);  // mlp buf; pO aliases it
  bf16*  qbuf = (bf16*)take((size_t)4096 * 768 * 2);
  bf16*  kbuf = (bf16*)take((size_t)4096 * 768 * 2);
  bf16*  vbuf = (bf16*)take((size_t)4096 * 768 * 2);
  bf16*  vTb  = (bf16*)take((size_t)4096 * 768 * 2);
  bf16*  abuf = (bf16*)take((size_t)4096 * 768 * 2);
  float* pM   = (float*)take((size_t)2 * 49152 * 4);
  float* pL   = (float*)take((size_t)2 * 49152 * 4);
  bf16*  pO   = mbuf;  // 12.6MB bf16, dead during attention (W1 writes after combine)

  const size_t wq1 = (size_t)2304 * 768, wo1 = (size_t)768 * 768,
               w11 = (size_t)3072 * 768, w21 = (size_t)768 * 3072;
  const size_t used = (size_t)(p - (char*)d_ws);
  const size_t wbytes = (wq1 + wo1 + w11 + w21) * 2;
  const bool hoist = ws_size >= used + 6 * wbytes + 8192;
  const int nl = hoist ? 6 : 1;
  bf16* qkvT = (bf16*)take(wq1 * 2 * nl);
  bf16* woT  = (bf16*)take(wo1 * 2 * nl);
  bf16* w1T  = (bf16*)take(w11 * 2 * nl);
  bf16* w2T  = (bf16*)take(w21 * 2 * nl);

  cast_x<<<3072, 256, 0, stream>>>(x_in, xw);
  if (hoist)
    wconv_all<<<5184, 256, 0, stream>>>(wqkv, wo, w1, w2, qkvT, woT, w1T, w2T, -1);

  for (int l = 0; l < 6; ++l) {
    if (!hoist)
      wconv_all<<<864, 256, 0, stream>>>(wqkv, wo, w1, w2, qkvT, woT, w1T, w2T, l);
    bf16* qkL = qkvT + (hoist ? (size_t)l * wq1 : 0);
    bf16* woL = woT  + (hoist ? (size_t)l * wo1 : 0);
    bf16* w1L = w1T  + (hoist ? (size_t)l * w11 : 0);
    bf16* w2L = w2T  + (hoist ? (size_t)l * w21 : 0);

    ln_kernel<<<4096, 256, 0, stream>>>(xw, ln1g + l * 768, ln1b + l * 768, h);
    gemm_s<EPI_QKV><<<dim3(18, 32), 256, 0, stream>>>(
        h, qkL, nullptr, nullptr, qbuf, kbuf, vbuf, outk, outv, l == 5 ? 1 : 0,
        4096, 2304, 768);
    vtrans<<<dim3(48, 32, 2), dim3(32, 8), 0, stream>>>(vbuf, vTb);
    attn_main<<<dim3(48, 32, 2), 64, 0, stream>>>(qbuf, kbuf, vTb, pO, pM, pL);
    attn_combine<<<1536, 256, 0, stream>>>(pO, pM, pL, abuf);
    gemm64_s<<<dim3(6, 64), 256, 0, stream>>>(
        abuf, woL, bo + l * 768, xw, xw, 4096, 768, 768);
    ln_kernel<<<4096, 256, 0, stream>>>(xw, ln2g + l * 768, ln2b + l * 768, h);
    gemm_s<EPI_GELU><<<dim3(24, 32), 256, 0, stream>>>(
        h, w1L, b1 + l * 3072, mbuf, nullptr, nullptr, nullptr, nullptr, nullptr, 0,
        4096, 3072, 768);
    // last layer writes the final residual directly to d_out (drops the memcpy)
    gemm64_s<<<dim3(6, 64), 256, 0, stream>>>(
        mbuf, w2L, b2 + l * 768, xw, (l == 5) ? outx : xw, 4096, 768, 3072);
  }
}